// Round 1
// baseline (186.888 us; speedup 1.0000x reference)
//
#include <hip/hip_runtime.h>

// LinearTextEmbedding: out[c][x][y] = (|bits[(x*1024+y) % 4096]| > 0.5) ? 1 : 0
// broadcast over 48 channels. Flat: out[o] = f(bits[o & 4095]) since both the
// image size (1048576) and channel stride are multiples of 4096.
//
// Pure write-bandwidth problem: 201.3 MB out, 16 KB in.

#define OUT_ELEMS (48u * 1024u * 1024u)   // 50331648 floats
#define N4        (OUT_ELEMS / 4u)        // 12582912 float4 stores

__global__ __launch_bounds__(256) void
LinearTextEmbedding_57604101374655_kernel(const float* __restrict__ bits,
                                          float4* __restrict__ out) {
    unsigned t = blockIdx.x * blockDim.x + threadIdx.x;
    if (t >= N4) return;
    // bit index for the 4 floats this thread writes: (t*4) & 4095, aligned to 4,
    // never straddles the 4096 wrap -> single float4 load at index t & 1023.
    float4 b = reinterpret_cast<const float4*>(bits)[t & 1023u];
    float4 v;
    v.x = (fabsf(b.x) > 0.5f) ? 1.0f : 0.0f;
    v.y = (fabsf(b.y) > 0.5f) ? 1.0f : 0.0f;
    v.z = (fabsf(b.z) > 0.5f) ? 1.0f : 0.0f;
    v.w = (fabsf(b.w) > 0.5f) ? 1.0f : 0.0f;
    out[t] = v;
}

extern "C" void kernel_launch(void* const* d_in, const int* in_sizes, int n_in,
                              void* d_out, int out_size, void* d_ws, size_t ws_size,
                              hipStream_t stream) {
    const float* bits = (const float*)d_in[0];
    float4* out = (float4*)d_out;
    const int block = 256;
    const int grid = (N4 + block - 1) / block;   // 49152 blocks
    LinearTextEmbedding_57604101374655_kernel<<<grid, block, 0, stream>>>(bits, out);
}